// Round 11
// baseline (423.210 us; speedup 1.0000x reference)
//
#include <hip/hip_runtime.h>
#include <math.h>

// PDELayer R12 (3rd submit; two prior benches lost to GPUAcquisitionTimeout):
// EXACT 100-step propagator via separable eigendecomposition.
// u_{n+1} = u + A u + u R + c,  A = D_alpha*T (rows), R = T*D_beta (cols),
// T = tridiag(1,-2,1) 48x48, c = frozen reflect-pad contribution.
// In eigenbases (A V_A = V_A Lam, R^T V_B = V_B Sig), uh = V_A^-1 u V_B^-T:
//   uh_100 = G (.) uh_0 + S (.) ch,  G = (1+lam_p+sig_q)^100,
//   S = sum_{k<100} (1+lam+sig)^k,  ch = rank-4 transform of c.
//
// R11 post-mortem: prop_kernel 213us @ VALUBusy 33%, Occupancy 31%, HBM 6.7%
// -- latency-bound, 4.6x its 46us fma floor. Its 39.9KB LDS caps 4 blocks/CU
// and 6 __syncthreads convoy the 4 waves, but scr[w]/vecs[w] are WAVE-PRIVATE
// so the barriers are pure overhead.
// R12: prop only -- 1-wave blocks (64 thr, grid 8192), scr 9984B -> 16
// blocks/CU (50% occupancy, 4 waves/SIMD), ALL barriers removed (same-wave
// LDS RAW ordering is compiler-inserted lgkmcnt). No math changes.
// eig_kernel/gs_kernel byte-identical to R11 (eig ~170us will now surface
// in top-5 for its first counter read).

// ---- ws float offsets ----
#define WS_LAM   0      // lamA[48] | sigB[48]
#define WS_QC0   96     // alpha0*VinvA[:,0][48] ; beta0*VinvB[:,0] at 192
#define WS_QC47  144    // alpha47*VinvA[:,47]   ; beta47*VinvB[:,47] at 240
#define WS_QTAB  288    // QLT[2304] (A) | QR[2304] (B at +2304): [k][p]=Vinv[p][k]
#define WS_PTAB  4896   // PLT[2304] (A) | PR[2304] (B at +2304): [k][p]=V[p][k]
#define WS_G     9504
#define WS_S     11808

__device__ __forceinline__ float frcp(float x) { return __builtin_amdgcn_rcpf(x); }

// =====================  K1: eigensolver (grid 2, block 64)  ================
__global__ __launch_bounds__(64) void eig_kernel(
    const float* __restrict__ pa1, const float* __restrict__ pa2,
    const float* __restrict__ pa3, const float* __restrict__ pb1,
    const float* __restrict__ pb2, const float* __restrict__ pb3,
    float* __restrict__ ws)
{
    __shared__ float sc[48], sd[48], se[48];
    __shared__ float sred[2];
    __shared__ float fD[48][49], fDL[48][49], fU1[48][49], fU2[48][49];
    __shared__ float sU[48][49];
    __shared__ unsigned char fP[48][48];

    const int which = blockIdx.x;            // 0: alpha/A, 1: beta/B
    const int l = threadIdx.x;

    // ---- phase 1: coefficient vector ----
    if (l < 48) {
        float t = 6.283185307179586f * ((float)l / 47.0f);
        float s = sinf(t), c = cosf(t);
        sc[l] = (which == 0)
            ? 0.1152f * (fabsf(pa1[0]) + fabsf(pa2[0]) * s + fabsf(pa3[0]) * c)
            : 0.2304f * (fabsf(pb1[0]) + fabsf(pb2[0]) * c + fabsf(pb3[0]) * s);
    }
    __syncthreads();

    // ---- phase 2: M = L^T D_c L (symmetric tridiagonal) ----
    if (l < 48) {
        float a2 = (float)(l + 2) / (float)(l + 1);      // a_l^2
        float d = a2 * sc[l];
        if (l < 47) {
            float b2 = (float)(l + 1) / (float)(l + 2);  // b_l^2
            d += b2 * sc[l + 1];
            se[l] = -sqrtf(b2) * sc[l + 1] * sqrtf((float)(l + 3) / (float)(l + 2));
        } else se[l] = 0.f;
        sd[l] = d;
    }
    __syncthreads();

    // ---- phase 3: Gershgorin bounds ----
    if (l == 0) {
        float lo = 1e30f, hi = -1e30f;
        for (int i = 0; i < 48; ++i) {
            float em = (i > 0) ? fabsf(se[i - 1]) : 0.f;
            float ep = (i < 47) ? fabsf(se[i]) : 0.f;
            lo = fminf(lo, sd[i] - em - ep);
            hi = fmaxf(hi, sd[i] + em + ep);
        }
        sred[0] = lo - 1e-6f; sred[1] = hi + 1e-6f;
    }
    __syncthreads();

    // ---- phase 4: Sturm bisection (32 steps, rcp), lane k -> mu_k ----
    float mu = 0.f;
    if (l < 48) {
        float lo = sred[0], hi = sred[1];
        for (int it = 0; it < 32; ++it) {
            float x = 0.5f * (lo + hi);
            int cnt = 0; float q = 1.0f;
            #pragma unroll 4
            for (int i = 0; i < 48; ++i) {
                float e2 = (i > 0) ? se[i - 1] * se[i - 1] : 0.f;
                q = sd[i] - x - e2 * frcp(q);
                if (fabsf(q) < 1e-30f) q = -1e-30f;
                cnt += (q < 0.f) ? 1 : 0;
            }
            if (cnt <= l) lo = x; else hi = x;
        }
        mu = 0.5f * (lo + hi);
        ws[WS_LAM + 48 * which + l] = -mu;   // eigenvalue of A (= -mu)
    }

    // ---- phase 5: pivoted-LU inverse iteration on (M - mu I) ----
    float x[48];
    if (l < 48) {
        for (int i = 0; i < 48; ++i) {
            fD[i][l]  = sd[i] - mu;
            fDL[i][l] = (i > 0)  ? se[i - 1] : 0.f;
            fU1[i][l] = (i < 47) ? se[i] : 0.f;
            fU2[i][l] = 0.f;
            fP[i][l]  = 0;
        }
        for (int i = 0; i < 47; ++i) {       // LAPACK gttrf
            float di = fD[i][l], sub = fDL[i + 1][l];
            if (fabsf(di) >= fabsf(sub)) {
                float fact = (di != 0.f) ? sub * frcp(di) : 0.f;
                fDL[i + 1][l] = fact;
                fD[i + 1][l] -= fact * fU1[i][l];
            } else {
                float fact = di * frcp(sub);
                fD[i][l] = sub; fDL[i + 1][l] = fact;
                float tmp = fU1[i][l];
                fU1[i][l] = fD[i + 1][l];
                fD[i + 1][l] = tmp - fact * fD[i + 1][l];
                if (i < 46) { fU2[i][l] = fU1[i + 1][l]; fU1[i + 1][l] = -fact * fU1[i + 1][l]; }
                fP[i][l] = 1;
            }
        }
        for (int i = 0; i < 48; ++i) {       // clamp + store reciprocal diag
            float d = fD[i][l];
            if (fabsf(d) < 1e-12f) d = (d >= 0.f) ? 1e-12f : -1e-12f;
            fD[i][l] = frcp(d);
        }
        #pragma unroll
        for (int i = 0; i < 48; ++i) {       // decorrelated pseudo-random rhs
            unsigned h = (unsigned)(i * 1664525u) + (unsigned)((l + 1) * 1013904223u);
            h ^= h >> 16; h *= 2654435761u; h ^= h >> 13;
            x[i] = (float)(h & 0xFFFF) * (1.0f / 65536.0f) - 0.5f;
        }
        for (int pass = 0; pass < 2; ++pass) {
            #pragma unroll
            for (int i = 0; i < 47; ++i) {   // forward (gtts2), x in regs
                float fact = fDL[i + 1][l];
                if (!fP[i][l]) {
                    x[i + 1] -= fact * x[i];
                } else {
                    float t1 = x[i];
                    x[i] = x[i + 1];
                    x[i + 1] = t1 - fact * x[i + 1];
                }
            }
            x[47] = x[47] * fD[47][l];       // fD holds reciprocals
            x[46] = (x[46] - fU1[46][l] * x[47]) * fD[46][l];
            #pragma unroll
            for (int i = 45; i >= 0; --i)
                x[i] = (x[i] - fU1[i][l] * x[i + 1] - fU2[i][l] * x[i + 2]) * fD[i][l];
            float n0 = 0.f, n1 = 0.f, n2 = 0.f, n3 = 0.f;
            #pragma unroll
            for (int i = 0; i < 48; i += 4) {
                n0 = fmaf(x[i], x[i], n0);     n1 = fmaf(x[i+1], x[i+1], n1);
                n2 = fmaf(x[i+2], x[i+2], n2); n3 = fmaf(x[i+3], x[i+3], n3);
            }
            float inv = __builtin_amdgcn_rsqf(fmaxf(n0 + n1 + n2 + n3, 1e-30f));
            #pragma unroll
            for (int i = 0; i < 48; ++i) x[i] *= inv;
        }
    }
    __syncthreads();

    // ---- phase 6: MGS across lanes (register x vs LDS column j) ----
    for (int j = 0; j < 48; ++j) {
        if (l == j) {
            #pragma unroll
            for (int i = 0; i < 48; ++i) sU[i][j] = x[i];
        }
        __syncthreads();
        if (l > j && l < 48) {
            float d0 = 0.f, d1 = 0.f, d2 = 0.f, d3 = 0.f;
            #pragma unroll
            for (int i = 0; i < 48; i += 4) {
                d0 = fmaf(sU[i][j],     x[i],     d0);
                d1 = fmaf(sU[i+1][j],   x[i+1],   d1);
                d2 = fmaf(sU[i+2][j],   x[i+2],   d2);
                d3 = fmaf(sU[i+3][j],   x[i+3],   d3);
            }
            float dot = (d0 + d1) + (d2 + d3);
            #pragma unroll
            for (int i = 0; i < 48; ++i) x[i] = fmaf(-dot, sU[i][j], x[i]);
            if (l == j + 1) {                // renormalize next pivot column
                float n0 = 0.f, n1 = 0.f, n2 = 0.f, n3 = 0.f;
                #pragma unroll
                for (int i = 0; i < 48; i += 4) {
                    n0 = fmaf(x[i], x[i], n0);     n1 = fmaf(x[i+1], x[i+1], n1);
                    n2 = fmaf(x[i+2], x[i+2], n2); n3 = fmaf(x[i+3], x[i+3], n3);
                }
                float inv = __builtin_amdgcn_rsqf(fmaxf(n0 + n1 + n2 + n3, 1e-30f));
                #pragma unroll
                for (int i = 0; i < 48; ++i) x[i] *= inv;
            }
        }
        __syncthreads();
    }

    // ---- phase 7: V column = L^-T U column (registers; folded consts) ----
    float v[48];
    if (l < 48) {
        v[47] = x[47] * (1.0f / 1.0103629710818451f);    // 1/sqrt(49/48)
        #pragma unroll
        for (int i = 46; i >= 0; --i) {
            float ai  = sqrtf((float)(i + 2) / (float)(i + 1));   // const-folded
            float bi  = -sqrtf((float)(i + 1) / (float)(i + 2));  // const-folded
            v[i] = (x[i] - bi * v[i + 1]) * (1.0f / ai);
        }
    }

    // ---- phase 8: tables. Vinv = U^T L^T (bidiagonal product of regs) ----
    if (l < 48) {
        #pragma unroll
        for (int i = 0; i < 48; ++i)         // Ptab[l][i] = V[i][l]
            ws[WS_PTAB + 2304 * which + l * 48 + i] = v[i];
        #pragma unroll
        for (int k = 0; k < 48; ++k) {       // Qtab[k][l] = Vinv[l][k]
            float ak = sqrtf((float)(k + 2) / (float)(k + 1));    // const-folded
            float val = ak * x[k];
            if (k > 0) val -= sqrtf((float)k / (float)(k + 1)) * x[k - 1];
            ws[WS_QTAB + 2304 * which + k * 48 + l] = val;
        }
        const float a0  = 1.4142135623730951f;            // sqrt(2)
        const float a47 = 1.0103629710818451f;            // sqrt(49/48)
        const float b46 = -0.98952851424086366f;          // -sqrt(47/48)
        ws[WS_QC0  + 96 * which + l] = sc[0]  * (a0 * x[0]);
        ws[WS_QC47 + 96 * which + l] = sc[47] * (a47 * x[47] + b46 * x[46]);
    }
}

// ==================  K2: G/S tables (grid 9, block 256)  ===================
__global__ __launch_bounds__(256) void gs_kernel(float* __restrict__ ws)
{
    int idx = blockIdx.x * 256 + threadIdx.x;
    if (idx >= 2304) return;
    int p = idx / 48, q = idx % 48;
    float d = ws[p] + ws[48 + q];           // lam_p + sig_q
    float r = 1.0f + d;
    float r2 = r * r, r4 = r2 * r2, r8 = r4 * r4;
    float r16 = r8 * r8, r32 = r16 * r16, r64 = r32 * r32;
    float G = r64 * r32 * r4;               // r^100
    float S;
    if (fabsf(d) > 1e-3f) S = (G - 1.0f) / d;
    else S = 100.f + d * (4950.f + d * 161700.f);
    ws[WS_G + idx] = G;
    ws[WS_S + idx] = S;
}

// ==========  K3: propagate (grid 8192, block 64 = 1 wave/image)  ===========
// scr/vecs are wave-private: NO barriers needed (same-wave LDS ordering is
// compiler-inserted lgkmcnt). 9984B LDS -> 16 blocks/CU, 4 waves/SIMD.
__global__ __launch_bounds__(64, 4) void prop_kernel(
    const float* __restrict__ u0, const float* __restrict__ ws,
    float* __restrict__ out)
{
    __shared__ float scr[2304];
    __shared__ float vecs[4][48];           // wt, wb, vl, vr

    const int lane = threadIdx.x;
    const int img = blockIdx.x;
    const int rq = lane & 15, cq = lane >> 4;
    const int p0 = 3 * rq, q0 = 12 * cq;
    const float* __restrict__ src = u0 + (size_t)img * 2304;
    float* __restrict__ dst = out + (size_t)img * 2304;
    const float* __restrict__ QLT = ws + WS_QTAB;
    const float* __restrict__ QR  = ws + WS_QTAB + 2304;
    const float* __restrict__ PLT = ws + WS_PTAB;
    const float* __restrict__ PR  = ws + WS_PTAB + 2304;
    const float* __restrict__ Gt  = ws + WS_G;
    const float* __restrict__ St  = ws + WS_S;

    float C[3][12], D[3][12];

    // ---- M1: t1 = V_A^-1 * u0 ----
    #pragma unroll
    for (int r = 0; r < 3; ++r)
        #pragma unroll
        for (int c = 0; c < 12; ++c) C[r][c] = 0.f;
    #pragma unroll 4
    for (int k = 0; k < 48; ++k) {
        float a0 = QLT[k * 48 + p0], a1 = QLT[k * 48 + p0 + 1], a2 = QLT[k * 48 + p0 + 2];
        float b[12];
        #pragma unroll
        for (int c = 0; c < 12; ++c) b[c] = src[k * 48 + q0 + c];
        #pragma unroll
        for (int c = 0; c < 12; ++c) {
            C[0][c] = fmaf(a0, b[c], C[0][c]);
            C[1][c] = fmaf(a1, b[c], C[1][c]);
            C[2][c] = fmaf(a2, b[c], C[2][c]);
        }
    }
    #pragma unroll
    for (int r = 0; r < 3; ++r)             // stage t1^T
        #pragma unroll
        for (int c = 0; c < 12; ++c) scr[(q0 + c) * 48 + p0 + r] = C[r][c];
    // boundary matvecs: wt=VinvB*Pt, wb=VinvB*Pb, vl=VinvA*Pl, vr=VinvA*Pr
    if (lane < 48) {
        float wt = 0.f, wb = 0.f, vl = 0.f, vr = 0.f;
        #pragma unroll 4
        for (int j = 0; j < 48; ++j) {
            float ptj = src[48 + j], pbj = src[46 * 48 + j];
            float plj = src[j * 48 + 1], prj = src[j * 48 + 46];
            float qr = QR[j * 48 + lane], ql = QLT[j * 48 + lane];
            wt = fmaf(qr, ptj, wt); wb = fmaf(qr, pbj, wb);
            vl = fmaf(ql, plj, vl); vr = fmaf(ql, prj, vr);
        }
        vecs[0][lane] = wt; vecs[1][lane] = wb;
        vecs[2][lane] = vl; vecs[3][lane] = vr;
    }
    // ---- M2: uh0 = t1 * V_B^-T ----
    #pragma unroll
    for (int r = 0; r < 3; ++r)
        #pragma unroll
        for (int c = 0; c < 12; ++c) D[r][c] = 0.f;
    #pragma unroll 4
    for (int j = 0; j < 48; ++j) {
        float a0 = scr[j * 48 + p0], a1 = scr[j * 48 + p0 + 1], a2 = scr[j * 48 + p0 + 2];
        float b[12];
        #pragma unroll
        for (int c = 0; c < 12; ++c) b[c] = QR[j * 48 + q0 + c];
        #pragma unroll
        for (int c = 0; c < 12; ++c) {
            D[0][c] = fmaf(a0, b[c], D[0][c]);
            D[1][c] = fmaf(a1, b[c], D[1][c]);
            D[2][c] = fmaf(a2, b[c], D[2][c]);
        }
    }
    // ---- combine: uhN = G .* uh0 + S .* ch ----
    #pragma unroll
    for (int r = 0; r < 3; ++r) {
        int p = p0 + r;
        float qc0v = ws[WS_QC0 + p], qc47v = ws[WS_QC47 + p];
        float vlp = vecs[2][p], vrp = vecs[3][p];
        #pragma unroll
        for (int c = 0; c < 12; ++c) {
            int q = q0 + c;
            float ch = qc0v * vecs[0][q] + qc47v * vecs[1][q]
                     + vlp * ws[WS_QC0 + 96 + q] + vrp * ws[WS_QC47 + 96 + q];
            scr[p * 48 + q] = Gt[p * 48 + q] * D[r][c] + St[p * 48 + q] * ch;
        }
    }
    // ---- M3: t2 = V_A * uhN ----
    #pragma unroll
    for (int r = 0; r < 3; ++r)
        #pragma unroll
        for (int c = 0; c < 12; ++c) C[r][c] = 0.f;
    #pragma unroll 4
    for (int k = 0; k < 48; ++k) {
        float a0 = PLT[k * 48 + p0], a1 = PLT[k * 48 + p0 + 1], a2 = PLT[k * 48 + p0 + 2];
        float b[12];
        #pragma unroll
        for (int c = 0; c < 12; ++c) b[c] = scr[k * 48 + q0 + c];
        #pragma unroll
        for (int c = 0; c < 12; ++c) {
            C[0][c] = fmaf(a0, b[c], C[0][c]);
            C[1][c] = fmaf(a1, b[c], C[1][c]);
            C[2][c] = fmaf(a2, b[c], C[2][c]);
        }
    }
    #pragma unroll
    for (int r = 0; r < 3; ++r)             // stage t2^T
        #pragma unroll
        for (int c = 0; c < 12; ++c) scr[(q0 + c) * 48 + p0 + r] = C[r][c];
    // ---- M4: uN = t2 * V_B^T ----
    #pragma unroll
    for (int r = 0; r < 3; ++r)
        #pragma unroll
        for (int c = 0; c < 12; ++c) D[r][c] = 0.f;
    #pragma unroll 4
    for (int q = 0; q < 48; ++q) {
        float a0 = scr[q * 48 + p0], a1 = scr[q * 48 + p0 + 1], a2 = scr[q * 48 + p0 + 2];
        float b[12];
        #pragma unroll
        for (int c = 0; c < 12; ++c) b[c] = PR[q * 48 + q0 + c];
        #pragma unroll
        for (int c = 0; c < 12; ++c) {
            D[0][c] = fmaf(a0, b[c], D[0][c]);
            D[1][c] = fmaf(a1, b[c], D[1][c]);
            D[2][c] = fmaf(a2, b[c], D[2][c]);
        }
    }
    #pragma unroll
    for (int r = 0; r < 3; ++r)
        #pragma unroll
        for (int c = 0; c < 12; ++c) dst[(p0 + r) * 48 + q0 + c] = D[r][c];
}

extern "C" void kernel_launch(void* const* d_in, const int* in_sizes, int n_in,
                              void* d_out, int out_size, void* d_ws, size_t ws_size,
                              hipStream_t stream) {
    const float* u0 = (const float*)d_in[0];
    float* ws = (float*)d_ws;
    eig_kernel<<<2, 64, 0, stream>>>(
        (const float*)d_in[1], (const float*)d_in[2], (const float*)d_in[3],
        (const float*)d_in[4], (const float*)d_in[5], (const float*)d_in[6], ws);
    gs_kernel<<<9, 256, 0, stream>>>(ws);
    prop_kernel<<<8192, 64, 0, stream>>>(u0, ws, (float*)d_out);
}

// Round 13
// 404.236 us; speedup vs baseline: 1.0469x; 1.0469x over previous
//
#include <hip/hip_runtime.h>
#include <math.h>

// PDELayer R13 (resubmit; R13 bench lost to GPUAcquisitionTimeout):
// EXACT 100-step propagator via separable eigendecomposition.
// u_{n+1} = u + A u + u R + c,  A = D_alpha*T (rows), R = T*D_beta (cols),
// T = tridiag(1,-2,1) 48x48, c = frozen reflect-pad contribution.
// In eigenbases (A V_A = V_A Lam, R^T V_B = V_B Sig), uh = V_A^-1 u V_B^-T:
//   uh_100 = G (.) uh_0 + S (.) ch,  G = (1+lam_p+sig_q)^100,
//   S = sum_{k<100} (1+lam+sig)^k,  ch = rank-4 transform of c.
//
// R12 post-mortem: __launch_bounds__(64,4) made the allocator cap at 64 VGPR
// (conservative 256/4 model) and SPILL the C/D accumulators: FETCH 38->76MB,
// WRITE 74->124MB, VALUBusy flat 31%, dur flat 220us -- occupancy gain (31->
// 41%) fully eaten by scratch stalls. R13: cap relaxed to (64,2) = 128 VGPR.
// Kernel needs ~100 live -> no spill; 10KB LDS still admits 16 blocks/CU ->
// runtime occupancy still 4 waves/SIMD. No other changes.
// eig_kernel/gs_kernel byte-identical (eig ~190us by subtraction; it will
// enter top-5 once prop drops below it -> first real counters next round).

// ---- ws float offsets ----
#define WS_LAM   0      // lamA[48] | sigB[48]
#define WS_QC0   96     // alpha0*VinvA[:,0][48] ; beta0*VinvB[:,0] at 192
#define WS_QC47  144    // alpha47*VinvA[:,47]   ; beta47*VinvB[:,47] at 240
#define WS_QTAB  288    // QLT[2304] (A) | QR[2304] (B at +2304): [k][p]=Vinv[p][k]
#define WS_PTAB  4896   // PLT[2304] (A) | PR[2304] (B at +2304): [k][p]=V[p][k]
#define WS_G     9504
#define WS_S     11808

__device__ __forceinline__ float frcp(float x) { return __builtin_amdgcn_rcpf(x); }

// =====================  K1: eigensolver (grid 2, block 64)  ================
__global__ __launch_bounds__(64) void eig_kernel(
    const float* __restrict__ pa1, const float* __restrict__ pa2,
    const float* __restrict__ pa3, const float* __restrict__ pb1,
    const float* __restrict__ pb2, const float* __restrict__ pb3,
    float* __restrict__ ws)
{
    __shared__ float sc[48], sd[48], se[48];
    __shared__ float sred[2];
    __shared__ float fD[48][49], fDL[48][49], fU1[48][49], fU2[48][49];
    __shared__ float sU[48][49];
    __shared__ unsigned char fP[48][48];

    const int which = blockIdx.x;            // 0: alpha/A, 1: beta/B
    const int l = threadIdx.x;

    // ---- phase 1: coefficient vector ----
    if (l < 48) {
        float t = 6.283185307179586f * ((float)l / 47.0f);
        float s = sinf(t), c = cosf(t);
        sc[l] = (which == 0)
            ? 0.1152f * (fabsf(pa1[0]) + fabsf(pa2[0]) * s + fabsf(pa3[0]) * c)
            : 0.2304f * (fabsf(pb1[0]) + fabsf(pb2[0]) * c + fabsf(pb3[0]) * s);
    }
    __syncthreads();

    // ---- phase 2: M = L^T D_c L (symmetric tridiagonal) ----
    if (l < 48) {
        float a2 = (float)(l + 2) / (float)(l + 1);      // a_l^2
        float d = a2 * sc[l];
        if (l < 47) {
            float b2 = (float)(l + 1) / (float)(l + 2);  // b_l^2
            d += b2 * sc[l + 1];
            se[l] = -sqrtf(b2) * sc[l + 1] * sqrtf((float)(l + 3) / (float)(l + 2));
        } else se[l] = 0.f;
        sd[l] = d;
    }
    __syncthreads();

    // ---- phase 3: Gershgorin bounds ----
    if (l == 0) {
        float lo = 1e30f, hi = -1e30f;
        for (int i = 0; i < 48; ++i) {
            float em = (i > 0) ? fabsf(se[i - 1]) : 0.f;
            float ep = (i < 47) ? fabsf(se[i]) : 0.f;
            lo = fminf(lo, sd[i] - em - ep);
            hi = fmaxf(hi, sd[i] + em + ep);
        }
        sred[0] = lo - 1e-6f; sred[1] = hi + 1e-6f;
    }
    __syncthreads();

    // ---- phase 4: Sturm bisection (32 steps, rcp), lane k -> mu_k ----
    float mu = 0.f;
    if (l < 48) {
        float lo = sred[0], hi = sred[1];
        for (int it = 0; it < 32; ++it) {
            float x = 0.5f * (lo + hi);
            int cnt = 0; float q = 1.0f;
            #pragma unroll 4
            for (int i = 0; i < 48; ++i) {
                float e2 = (i > 0) ? se[i - 1] * se[i - 1] : 0.f;
                q = sd[i] - x - e2 * frcp(q);
                if (fabsf(q) < 1e-30f) q = -1e-30f;
                cnt += (q < 0.f) ? 1 : 0;
            }
            if (cnt <= l) lo = x; else hi = x;
        }
        mu = 0.5f * (lo + hi);
        ws[WS_LAM + 48 * which + l] = -mu;   // eigenvalue of A (= -mu)
    }

    // ---- phase 5: pivoted-LU inverse iteration on (M - mu I) ----
    float x[48];
    if (l < 48) {
        for (int i = 0; i < 48; ++i) {
            fD[i][l]  = sd[i] - mu;
            fDL[i][l] = (i > 0)  ? se[i - 1] : 0.f;
            fU1[i][l] = (i < 47) ? se[i] : 0.f;
            fU2[i][l] = 0.f;
            fP[i][l]  = 0;
        }
        for (int i = 0; i < 47; ++i) {       // LAPACK gttrf
            float di = fD[i][l], sub = fDL[i + 1][l];
            if (fabsf(di) >= fabsf(sub)) {
                float fact = (di != 0.f) ? sub * frcp(di) : 0.f;
                fDL[i + 1][l] = fact;
                fD[i + 1][l] -= fact * fU1[i][l];
            } else {
                float fact = di * frcp(sub);
                fD[i][l] = sub; fDL[i + 1][l] = fact;
                float tmp = fU1[i][l];
                fU1[i][l] = fD[i + 1][l];
                fD[i + 1][l] = tmp - fact * fD[i + 1][l];
                if (i < 46) { fU2[i][l] = fU1[i + 1][l]; fU1[i + 1][l] = -fact * fU1[i + 1][l]; }
                fP[i][l] = 1;
            }
        }
        for (int i = 0; i < 48; ++i) {       // clamp + store reciprocal diag
            float d = fD[i][l];
            if (fabsf(d) < 1e-12f) d = (d >= 0.f) ? 1e-12f : -1e-12f;
            fD[i][l] = frcp(d);
        }
        #pragma unroll
        for (int i = 0; i < 48; ++i) {       // decorrelated pseudo-random rhs
            unsigned h = (unsigned)(i * 1664525u) + (unsigned)((l + 1) * 1013904223u);
            h ^= h >> 16; h *= 2654435761u; h ^= h >> 13;
            x[i] = (float)(h & 0xFFFF) * (1.0f / 65536.0f) - 0.5f;
        }
        for (int pass = 0; pass < 2; ++pass) {
            #pragma unroll
            for (int i = 0; i < 47; ++i) {   // forward (gtts2), x in regs
                float fact = fDL[i + 1][l];
                if (!fP[i][l]) {
                    x[i + 1] -= fact * x[i];
                } else {
                    float t1 = x[i];
                    x[i] = x[i + 1];
                    x[i + 1] = t1 - fact * x[i + 1];
                }
            }
            x[47] = x[47] * fD[47][l];       // fD holds reciprocals
            x[46] = (x[46] - fU1[46][l] * x[47]) * fD[46][l];
            #pragma unroll
            for (int i = 45; i >= 0; --i)
                x[i] = (x[i] - fU1[i][l] * x[i + 1] - fU2[i][l] * x[i + 2]) * fD[i][l];
            float n0 = 0.f, n1 = 0.f, n2 = 0.f, n3 = 0.f;
            #pragma unroll
            for (int i = 0; i < 48; i += 4) {
                n0 = fmaf(x[i], x[i], n0);     n1 = fmaf(x[i+1], x[i+1], n1);
                n2 = fmaf(x[i+2], x[i+2], n2); n3 = fmaf(x[i+3], x[i+3], n3);
            }
            float inv = __builtin_amdgcn_rsqf(fmaxf(n0 + n1 + n2 + n3, 1e-30f));
            #pragma unroll
            for (int i = 0; i < 48; ++i) x[i] *= inv;
        }
    }
    __syncthreads();

    // ---- phase 6: MGS across lanes (register x vs LDS column j) ----
    for (int j = 0; j < 48; ++j) {
        if (l == j) {
            #pragma unroll
            for (int i = 0; i < 48; ++i) sU[i][j] = x[i];
        }
        __syncthreads();
        if (l > j && l < 48) {
            float d0 = 0.f, d1 = 0.f, d2 = 0.f, d3 = 0.f;
            #pragma unroll
            for (int i = 0; i < 48; i += 4) {
                d0 = fmaf(sU[i][j],     x[i],     d0);
                d1 = fmaf(sU[i+1][j],   x[i+1],   d1);
                d2 = fmaf(sU[i+2][j],   x[i+2],   d2);
                d3 = fmaf(sU[i+3][j],   x[i+3],   d3);
            }
            float dot = (d0 + d1) + (d2 + d3);
            #pragma unroll
            for (int i = 0; i < 48; ++i) x[i] = fmaf(-dot, sU[i][j], x[i]);
            if (l == j + 1) {                // renormalize next pivot column
                float n0 = 0.f, n1 = 0.f, n2 = 0.f, n3 = 0.f;
                #pragma unroll
                for (int i = 0; i < 48; i += 4) {
                    n0 = fmaf(x[i], x[i], n0);     n1 = fmaf(x[i+1], x[i+1], n1);
                    n2 = fmaf(x[i+2], x[i+2], n2); n3 = fmaf(x[i+3], x[i+3], n3);
                }
                float inv = __builtin_amdgcn_rsqf(fmaxf(n0 + n1 + n2 + n3, 1e-30f));
                #pragma unroll
                for (int i = 0; i < 48; ++i) x[i] *= inv;
            }
        }
        __syncthreads();
    }

    // ---- phase 7: V column = L^-T U column (registers; folded consts) ----
    float v[48];
    if (l < 48) {
        v[47] = x[47] * (1.0f / 1.0103629710818451f);    // 1/sqrt(49/48)
        #pragma unroll
        for (int i = 46; i >= 0; --i) {
            float ai  = sqrtf((float)(i + 2) / (float)(i + 1));   // const-folded
            float bi  = -sqrtf((float)(i + 1) / (float)(i + 2));  // const-folded
            v[i] = (x[i] - bi * v[i + 1]) * (1.0f / ai);
        }
    }

    // ---- phase 8: tables. Vinv = U^T L^T (bidiagonal product of regs) ----
    if (l < 48) {
        #pragma unroll
        for (int i = 0; i < 48; ++i)         // Ptab[l][i] = V[i][l]
            ws[WS_PTAB + 2304 * which + l * 48 + i] = v[i];
        #pragma unroll
        for (int k = 0; k < 48; ++k) {       // Qtab[k][l] = Vinv[l][k]
            float ak = sqrtf((float)(k + 2) / (float)(k + 1));    // const-folded
            float val = ak * x[k];
            if (k > 0) val -= sqrtf((float)k / (float)(k + 1)) * x[k - 1];
            ws[WS_QTAB + 2304 * which + k * 48 + l] = val;
        }
        const float a0  = 1.4142135623730951f;            // sqrt(2)
        const float a47 = 1.0103629710818451f;            // sqrt(49/48)
        const float b46 = -0.98952851424086366f;          // -sqrt(47/48)
        ws[WS_QC0  + 96 * which + l] = sc[0]  * (a0 * x[0]);
        ws[WS_QC47 + 96 * which + l] = sc[47] * (a47 * x[47] + b46 * x[46]);
    }
}

// ==================  K2: G/S tables (grid 9, block 256)  ===================
__global__ __launch_bounds__(256) void gs_kernel(float* __restrict__ ws)
{
    int idx = blockIdx.x * 256 + threadIdx.x;
    if (idx >= 2304) return;
    int p = idx / 48, q = idx % 48;
    float d = ws[p] + ws[48 + q];           // lam_p + sig_q
    float r = 1.0f + d;
    float r2 = r * r, r4 = r2 * r2, r8 = r4 * r4;
    float r16 = r8 * r8, r32 = r16 * r16, r64 = r32 * r32;
    float G = r64 * r32 * r4;               // r^100
    float S;
    if (fabsf(d) > 1e-3f) S = (G - 1.0f) / d;
    else S = 100.f + d * (4950.f + d * 161700.f);
    ws[WS_G + idx] = G;
    ws[WS_S + idx] = S;
}

// ==========  K3: propagate (grid 8192, block 64 = 1 wave/image)  ===========
// scr/vecs are wave-private: NO barriers needed (same-wave LDS ordering is
// compiler-inserted lgkmcnt). 10KB LDS -> 16 blocks/CU; (64,2) caps VGPR at
// 128 (kernel needs ~100, no spill) -> runtime occupancy 4 waves/SIMD.
__global__ __launch_bounds__(64, 2) void prop_kernel(
    const float* __restrict__ u0, const float* __restrict__ ws,
    float* __restrict__ out)
{
    __shared__ float scr[2304];
    __shared__ float vecs[4][48];           // wt, wb, vl, vr

    const int lane = threadIdx.x;
    const int img = blockIdx.x;
    const int rq = lane & 15, cq = lane >> 4;
    const int p0 = 3 * rq, q0 = 12 * cq;
    const float* __restrict__ src = u0 + (size_t)img * 2304;
    float* __restrict__ dst = out + (size_t)img * 2304;
    const float* __restrict__ QLT = ws + WS_QTAB;
    const float* __restrict__ QR  = ws + WS_QTAB + 2304;
    const float* __restrict__ PLT = ws + WS_PTAB;
    const float* __restrict__ PR  = ws + WS_PTAB + 2304;
    const float* __restrict__ Gt  = ws + WS_G;
    const float* __restrict__ St  = ws + WS_S;

    float C[3][12], D[3][12];

    // ---- M1: t1 = V_A^-1 * u0 ----
    #pragma unroll
    for (int r = 0; r < 3; ++r)
        #pragma unroll
        for (int c = 0; c < 12; ++c) C[r][c] = 0.f;
    #pragma unroll 4
    for (int k = 0; k < 48; ++k) {
        float a0 = QLT[k * 48 + p0], a1 = QLT[k * 48 + p0 + 1], a2 = QLT[k * 48 + p0 + 2];
        float b[12];
        #pragma unroll
        for (int c = 0; c < 12; ++c) b[c] = src[k * 48 + q0 + c];
        #pragma unroll
        for (int c = 0; c < 12; ++c) {
            C[0][c] = fmaf(a0, b[c], C[0][c]);
            C[1][c] = fmaf(a1, b[c], C[1][c]);
            C[2][c] = fmaf(a2, b[c], C[2][c]);
        }
    }
    #pragma unroll
    for (int r = 0; r < 3; ++r)             // stage t1^T
        #pragma unroll
        for (int c = 0; c < 12; ++c) scr[(q0 + c) * 48 + p0 + r] = C[r][c];
    // boundary matvecs: wt=VinvB*Pt, wb=VinvB*Pb, vl=VinvA*Pl, vr=VinvA*Pr
    if (lane < 48) {
        float wt = 0.f, wb = 0.f, vl = 0.f, vr = 0.f;
        #pragma unroll 4
        for (int j = 0; j < 48; ++j) {
            float ptj = src[48 + j], pbj = src[46 * 48 + j];
            float plj = src[j * 48 + 1], prj = src[j * 48 + 46];
            float qr = QR[j * 48 + lane], ql = QLT[j * 48 + lane];
            wt = fmaf(qr, ptj, wt); wb = fmaf(qr, pbj, wb);
            vl = fmaf(ql, plj, vl); vr = fmaf(ql, prj, vr);
        }
        vecs[0][lane] = wt; vecs[1][lane] = wb;
        vecs[2][lane] = vl; vecs[3][lane] = vr;
    }
    // ---- M2: uh0 = t1 * V_B^-T ----
    #pragma unroll
    for (int r = 0; r < 3; ++r)
        #pragma unroll
        for (int c = 0; c < 12; ++c) D[r][c] = 0.f;
    #pragma unroll 4
    for (int j = 0; j < 48; ++j) {
        float a0 = scr[j * 48 + p0], a1 = scr[j * 48 + p0 + 1], a2 = scr[j * 48 + p0 + 2];
        float b[12];
        #pragma unroll
        for (int c = 0; c < 12; ++c) b[c] = QR[j * 48 + q0 + c];
        #pragma unroll
        for (int c = 0; c < 12; ++c) {
            D[0][c] = fmaf(a0, b[c], D[0][c]);
            D[1][c] = fmaf(a1, b[c], D[1][c]);
            D[2][c] = fmaf(a2, b[c], D[2][c]);
        }
    }
    // ---- combine: uhN = G .* uh0 + S .* ch ----
    #pragma unroll
    for (int r = 0; r < 3; ++r) {
        int p = p0 + r;
        float qc0v = ws[WS_QC0 + p], qc47v = ws[WS_QC47 + p];
        float vlp = vecs[2][p], vrp = vecs[3][p];
        #pragma unroll
        for (int c = 0; c < 12; ++c) {
            int q = q0 + c;
            float ch = qc0v * vecs[0][q] + qc47v * vecs[1][q]
                     + vlp * ws[WS_QC0 + 96 + q] + vrp * ws[WS_QC47 + 96 + q];
            scr[p * 48 + q] = Gt[p * 48 + q] * D[r][c] + St[p * 48 + q] * ch;
        }
    }
    // ---- M3: t2 = V_A * uhN ----
    #pragma unroll
    for (int r = 0; r < 3; ++r)
        #pragma unroll
        for (int c = 0; c < 12; ++c) C[r][c] = 0.f;
    #pragma unroll 4
    for (int k = 0; k < 48; ++k) {
        float a0 = PLT[k * 48 + p0], a1 = PLT[k * 48 + p0 + 1], a2 = PLT[k * 48 + p0 + 2];
        float b[12];
        #pragma unroll
        for (int c = 0; c < 12; ++c) b[c] = scr[k * 48 + q0 + c];
        #pragma unroll
        for (int c = 0; c < 12; ++c) {
            C[0][c] = fmaf(a0, b[c], C[0][c]);
            C[1][c] = fmaf(a1, b[c], C[1][c]);
            C[2][c] = fmaf(a2, b[c], C[2][c]);
        }
    }
    #pragma unroll
    for (int r = 0; r < 3; ++r)             // stage t2^T
        #pragma unroll
        for (int c = 0; c < 12; ++c) scr[(q0 + c) * 48 + p0 + r] = C[r][c];
    // ---- M4: uN = t2 * V_B^T ----
    #pragma unroll
    for (int r = 0; r < 3; ++r)
        #pragma unroll
        for (int c = 0; c < 12; ++c) D[r][c] = 0.f;
    #pragma unroll 4
    for (int q = 0; q < 48; ++q) {
        float a0 = scr[q * 48 + p0], a1 = scr[q * 48 + p0 + 1], a2 = scr[q * 48 + p0 + 2];
        float b[12];
        #pragma unroll
        for (int c = 0; c < 12; ++c) b[c] = PR[q * 48 + q0 + c];
        #pragma unroll
        for (int c = 0; c < 12; ++c) {
            D[0][c] = fmaf(a0, b[c], D[0][c]);
            D[1][c] = fmaf(a1, b[c], D[1][c]);
            D[2][c] = fmaf(a2, b[c], D[2][c]);
        }
    }
    #pragma unroll
    for (int r = 0; r < 3; ++r)
        #pragma unroll
        for (int c = 0; c < 12; ++c) dst[(p0 + r) * 48 + q0 + c] = D[r][c];
}

extern "C" void kernel_launch(void* const* d_in, const int* in_sizes, int n_in,
                              void* d_out, int out_size, void* d_ws, size_t ws_size,
                              hipStream_t stream) {
    const float* u0 = (const float*)d_in[0];
    float* ws = (float*)d_ws;
    eig_kernel<<<2, 64, 0, stream>>>(
        (const float*)d_in[1], (const float*)d_in[2], (const float*)d_in[3],
        (const float*)d_in[4], (const float*)d_in[5], (const float*)d_in[6], ws);
    gs_kernel<<<9, 256, 0, stream>>>(ws);
    prop_kernel<<<8192, 64, 0, stream>>>(u0, ws, (float*)d_out);
}

// Round 14
// 396.326 us; speedup vs baseline: 1.0678x; 1.0200x over previous
//
#include <hip/hip_runtime.h>
#include <math.h>

// PDELayer R14: EXACT 100-step propagator via separable eigendecomposition.
// u_{n+1} = u + A u + u R + c,  A = D_alpha*T (rows), R = T*D_beta (cols),
// T = tridiag(1,-2,1) 48x48, c = frozen reflect-pad contribution.
// In eigenbases (A V_A = V_A Lam, R^T V_B = V_B Sig), uh = V_A^-1 u V_B^-T:
//   uh_100 = G (.) uh_0 + S (.) ch,  G = (1+lam_p+sig_q)^100,
//   S = sum_{k<100} (1+lam+sig)^k,  ch = rank-4 transform of c.
//
// R13 post-mortem: spill fixed (VGPR 72, FETCH 38MB) but prop only 200us,
// VALUBusy 34% / Occupancy 31% IDENTICAL to the 4-wave R11 version ->
// barriers were never the stall; 66% of wall is memory-latency stall.
// Root cause found via G13 audit: ALL b-row loads were 12 scalar
// global_load_dword / ds_read_b32 per k (hipcc can't prove alignment).
// Offsets (48k+12cq)*4B are provably 16B-aligned -> R14 vectorizes every
// quad access to float4: src/QR/PR global loads, scr LDS reads (ds_read_
// b128), G/S table loads, combine scr writes, dst stores. ~2.5x fewer
// VMEM/LDS issue slots, 4x fewer dependent load completions per quad.
// eig_kernel/gs_kernel byte-identical to R11/R13 (eig ~200us will top the
// top-5 once prop drops -> first real eig counters next round).

// ---- ws float offsets ----
#define WS_LAM   0      // lamA[48] | sigB[48]
#define WS_QC0   96     // alpha0*VinvA[:,0][48] ; beta0*VinvB[:,0] at 192
#define WS_QC47  144    // alpha47*VinvA[:,47]   ; beta47*VinvB[:,47] at 240
#define WS_QTAB  288    // QLT[2304] (A) | QR[2304] (B at +2304): [k][p]=Vinv[p][k]
#define WS_PTAB  4896   // PLT[2304] (A) | PR[2304] (B at +2304): [k][p]=V[p][k]
#define WS_G     9504
#define WS_S     11808

typedef float v4 __attribute__((ext_vector_type(4)));

__device__ __forceinline__ float frcp(float x) { return __builtin_amdgcn_rcpf(x); }

// =====================  K1: eigensolver (grid 2, block 64)  ================
__global__ __launch_bounds__(64) void eig_kernel(
    const float* __restrict__ pa1, const float* __restrict__ pa2,
    const float* __restrict__ pa3, const float* __restrict__ pb1,
    const float* __restrict__ pb2, const float* __restrict__ pb3,
    float* __restrict__ ws)
{
    __shared__ float sc[48], sd[48], se[48];
    __shared__ float sred[2];
    __shared__ float fD[48][49], fDL[48][49], fU1[48][49], fU2[48][49];
    __shared__ float sU[48][49];
    __shared__ unsigned char fP[48][48];

    const int which = blockIdx.x;            // 0: alpha/A, 1: beta/B
    const int l = threadIdx.x;

    // ---- phase 1: coefficient vector ----
    if (l < 48) {
        float t = 6.283185307179586f * ((float)l / 47.0f);
        float s = sinf(t), c = cosf(t);
        sc[l] = (which == 0)
            ? 0.1152f * (fabsf(pa1[0]) + fabsf(pa2[0]) * s + fabsf(pa3[0]) * c)
            : 0.2304f * (fabsf(pb1[0]) + fabsf(pb2[0]) * c + fabsf(pb3[0]) * s);
    }
    __syncthreads();

    // ---- phase 2: M = L^T D_c L (symmetric tridiagonal) ----
    if (l < 48) {
        float a2 = (float)(l + 2) / (float)(l + 1);      // a_l^2
        float d = a2 * sc[l];
        if (l < 47) {
            float b2 = (float)(l + 1) / (float)(l + 2);  // b_l^2
            d += b2 * sc[l + 1];
            se[l] = -sqrtf(b2) * sc[l + 1] * sqrtf((float)(l + 3) / (float)(l + 2));
        } else se[l] = 0.f;
        sd[l] = d;
    }
    __syncthreads();

    // ---- phase 3: Gershgorin bounds ----
    if (l == 0) {
        float lo = 1e30f, hi = -1e30f;
        for (int i = 0; i < 48; ++i) {
            float em = (i > 0) ? fabsf(se[i - 1]) : 0.f;
            float ep = (i < 47) ? fabsf(se[i]) : 0.f;
            lo = fminf(lo, sd[i] - em - ep);
            hi = fmaxf(hi, sd[i] + em + ep);
        }
        sred[0] = lo - 1e-6f; sred[1] = hi + 1e-6f;
    }
    __syncthreads();

    // ---- phase 4: Sturm bisection (32 steps, rcp), lane k -> mu_k ----
    float mu = 0.f;
    if (l < 48) {
        float lo = sred[0], hi = sred[1];
        for (int it = 0; it < 32; ++it) {
            float x = 0.5f * (lo + hi);
            int cnt = 0; float q = 1.0f;
            #pragma unroll 4
            for (int i = 0; i < 48; ++i) {
                float e2 = (i > 0) ? se[i - 1] * se[i - 1] : 0.f;
                q = sd[i] - x - e2 * frcp(q);
                if (fabsf(q) < 1e-30f) q = -1e-30f;
                cnt += (q < 0.f) ? 1 : 0;
            }
            if (cnt <= l) lo = x; else hi = x;
        }
        mu = 0.5f * (lo + hi);
        ws[WS_LAM + 48 * which + l] = -mu;   // eigenvalue of A (= -mu)
    }

    // ---- phase 5: pivoted-LU inverse iteration on (M - mu I) ----
    float x[48];
    if (l < 48) {
        for (int i = 0; i < 48; ++i) {
            fD[i][l]  = sd[i] - mu;
            fDL[i][l] = (i > 0)  ? se[i - 1] : 0.f;
            fU1[i][l] = (i < 47) ? se[i] : 0.f;
            fU2[i][l] = 0.f;
            fP[i][l]  = 0;
        }
        for (int i = 0; i < 47; ++i) {       // LAPACK gttrf
            float di = fD[i][l], sub = fDL[i + 1][l];
            if (fabsf(di) >= fabsf(sub)) {
                float fact = (di != 0.f) ? sub * frcp(di) : 0.f;
                fDL[i + 1][l] = fact;
                fD[i + 1][l] -= fact * fU1[i][l];
            } else {
                float fact = di * frcp(sub);
                fD[i][l] = sub; fDL[i + 1][l] = fact;
                float tmp = fU1[i][l];
                fU1[i][l] = fD[i + 1][l];
                fD[i + 1][l] = tmp - fact * fD[i + 1][l];
                if (i < 46) { fU2[i][l] = fU1[i + 1][l]; fU1[i + 1][l] = -fact * fU1[i + 1][l]; }
                fP[i][l] = 1;
            }
        }
        for (int i = 0; i < 48; ++i) {       // clamp + store reciprocal diag
            float d = fD[i][l];
            if (fabsf(d) < 1e-12f) d = (d >= 0.f) ? 1e-12f : -1e-12f;
            fD[i][l] = frcp(d);
        }
        #pragma unroll
        for (int i = 0; i < 48; ++i) {       // decorrelated pseudo-random rhs
            unsigned h = (unsigned)(i * 1664525u) + (unsigned)((l + 1) * 1013904223u);
            h ^= h >> 16; h *= 2654435761u; h ^= h >> 13;
            x[i] = (float)(h & 0xFFFF) * (1.0f / 65536.0f) - 0.5f;
        }
        for (int pass = 0; pass < 2; ++pass) {
            #pragma unroll
            for (int i = 0; i < 47; ++i) {   // forward (gtts2), x in regs
                float fact = fDL[i + 1][l];
                if (!fP[i][l]) {
                    x[i + 1] -= fact * x[i];
                } else {
                    float t1 = x[i];
                    x[i] = x[i + 1];
                    x[i + 1] = t1 - fact * x[i + 1];
                }
            }
            x[47] = x[47] * fD[47][l];       // fD holds reciprocals
            x[46] = (x[46] - fU1[46][l] * x[47]) * fD[46][l];
            #pragma unroll
            for (int i = 45; i >= 0; --i)
                x[i] = (x[i] - fU1[i][l] * x[i + 1] - fU2[i][l] * x[i + 2]) * fD[i][l];
            float n0 = 0.f, n1 = 0.f, n2 = 0.f, n3 = 0.f;
            #pragma unroll
            for (int i = 0; i < 48; i += 4) {
                n0 = fmaf(x[i], x[i], n0);     n1 = fmaf(x[i+1], x[i+1], n1);
                n2 = fmaf(x[i+2], x[i+2], n2); n3 = fmaf(x[i+3], x[i+3], n3);
            }
            float inv = __builtin_amdgcn_rsqf(fmaxf(n0 + n1 + n2 + n3, 1e-30f));
            #pragma unroll
            for (int i = 0; i < 48; ++i) x[i] *= inv;
        }
    }
    __syncthreads();

    // ---- phase 6: MGS across lanes (register x vs LDS column j) ----
    for (int j = 0; j < 48; ++j) {
        if (l == j) {
            #pragma unroll
            for (int i = 0; i < 48; ++i) sU[i][j] = x[i];
        }
        __syncthreads();
        if (l > j && l < 48) {
            float d0 = 0.f, d1 = 0.f, d2 = 0.f, d3 = 0.f;
            #pragma unroll
            for (int i = 0; i < 48; i += 4) {
                d0 = fmaf(sU[i][j],     x[i],     d0);
                d1 = fmaf(sU[i+1][j],   x[i+1],   d1);
                d2 = fmaf(sU[i+2][j],   x[i+2],   d2);
                d3 = fmaf(sU[i+3][j],   x[i+3],   d3);
            }
            float dot = (d0 + d1) + (d2 + d3);
            #pragma unroll
            for (int i = 0; i < 48; ++i) x[i] = fmaf(-dot, sU[i][j], x[i]);
            if (l == j + 1) {                // renormalize next pivot column
                float n0 = 0.f, n1 = 0.f, n2 = 0.f, n3 = 0.f;
                #pragma unroll
                for (int i = 0; i < 48; i += 4) {
                    n0 = fmaf(x[i], x[i], n0);     n1 = fmaf(x[i+1], x[i+1], n1);
                    n2 = fmaf(x[i+2], x[i+2], n2); n3 = fmaf(x[i+3], x[i+3], n3);
                }
                float inv = __builtin_amdgcn_rsqf(fmaxf(n0 + n1 + n2 + n3, 1e-30f));
                #pragma unroll
                for (int i = 0; i < 48; ++i) x[i] *= inv;
            }
        }
        __syncthreads();
    }

    // ---- phase 7: V column = L^-T U column (registers; folded consts) ----
    float v[48];
    if (l < 48) {
        v[47] = x[47] * (1.0f / 1.0103629710818451f);    // 1/sqrt(49/48)
        #pragma unroll
        for (int i = 46; i >= 0; --i) {
            float ai  = sqrtf((float)(i + 2) / (float)(i + 1));   // const-folded
            float bi  = -sqrtf((float)(i + 1) / (float)(i + 2));  // const-folded
            v[i] = (x[i] - bi * v[i + 1]) * (1.0f / ai);
        }
    }

    // ---- phase 8: tables. Vinv = U^T L^T (bidiagonal product of regs) ----
    if (l < 48) {
        #pragma unroll
        for (int i = 0; i < 48; ++i)         // Ptab[l][i] = V[i][l]
            ws[WS_PTAB + 2304 * which + l * 48 + i] = v[i];
        #pragma unroll
        for (int k = 0; k < 48; ++k) {       // Qtab[k][l] = Vinv[l][k]
            float ak = sqrtf((float)(k + 2) / (float)(k + 1));    // const-folded
            float val = ak * x[k];
            if (k > 0) val -= sqrtf((float)k / (float)(k + 1)) * x[k - 1];
            ws[WS_QTAB + 2304 * which + k * 48 + l] = val;
        }
        const float a0  = 1.4142135623730951f;            // sqrt(2)
        const float a47 = 1.0103629710818451f;            // sqrt(49/48)
        const float b46 = -0.98952851424086366f;          // -sqrt(47/48)
        ws[WS_QC0  + 96 * which + l] = sc[0]  * (a0 * x[0]);
        ws[WS_QC47 + 96 * which + l] = sc[47] * (a47 * x[47] + b46 * x[46]);
    }
}

// ==================  K2: G/S tables (grid 9, block 256)  ===================
__global__ __launch_bounds__(256) void gs_kernel(float* __restrict__ ws)
{
    int idx = blockIdx.x * 256 + threadIdx.x;
    if (idx >= 2304) return;
    int p = idx / 48, q = idx % 48;
    float d = ws[p] + ws[48 + q];           // lam_p + sig_q
    float r = 1.0f + d;
    float r2 = r * r, r4 = r2 * r2, r8 = r4 * r4;
    float r16 = r8 * r8, r32 = r16 * r16, r64 = r32 * r32;
    float G = r64 * r32 * r4;               // r^100
    float S;
    if (fabsf(d) > 1e-3f) S = (G - 1.0f) / d;
    else S = 100.f + d * (4950.f + d * 161700.f);
    ws[WS_G + idx] = G;
    ws[WS_S + idx] = S;
}

// ==========  K3: propagate (grid 8192, block 64 = 1 wave/image)  ===========
// scr/vecs wave-private, no barriers. All quad accesses (offsets (48k+12cq)
// are 16B-aligned) vectorized to float4 / ds_read_b128 / dwordx4 stores.
__global__ __launch_bounds__(64, 2) void prop_kernel(
    const float* __restrict__ u0, const float* __restrict__ ws,
    float* __restrict__ out)
{
    __shared__ float scr[2304];
    __shared__ float vecs[4][48];           // wt, wb, vl, vr

    const int lane = threadIdx.x;
    const int img = blockIdx.x;
    const int rq = lane & 15, cq = lane >> 4;
    const int p0 = 3 * rq, q0 = 12 * cq;
    const float* __restrict__ src = u0 + (size_t)img * 2304;
    float* __restrict__ dst = out + (size_t)img * 2304;
    const float* __restrict__ QLT = ws + WS_QTAB;
    const float* __restrict__ QR  = ws + WS_QTAB + 2304;
    const float* __restrict__ PLT = ws + WS_PTAB;
    const float* __restrict__ PR  = ws + WS_PTAB + 2304;
    const float* __restrict__ Gt  = ws + WS_G;
    const float* __restrict__ St  = ws + WS_S;

    float C[3][12], D[3][12];

    // ---- M1: t1 = V_A^-1 * u0 ----
    #pragma unroll
    for (int r = 0; r < 3; ++r)
        #pragma unroll
        for (int c = 0; c < 12; ++c) C[r][c] = 0.f;
    #pragma unroll 4
    for (int k = 0; k < 48; ++k) {
        float a0 = QLT[k * 48 + p0], a1 = QLT[k * 48 + p0 + 1], a2 = QLT[k * 48 + p0 + 2];
        const v4 b0 = *(const v4*)&src[k * 48 + q0];
        const v4 b1 = *(const v4*)&src[k * 48 + q0 + 4];
        const v4 b2 = *(const v4*)&src[k * 48 + q0 + 8];
        #pragma unroll
        for (int c = 0; c < 4; ++c) {
            C[0][c]     = fmaf(a0, b0[c], C[0][c]);
            C[1][c]     = fmaf(a1, b0[c], C[1][c]);
            C[2][c]     = fmaf(a2, b0[c], C[2][c]);
            C[0][c + 4] = fmaf(a0, b1[c], C[0][c + 4]);
            C[1][c + 4] = fmaf(a1, b1[c], C[1][c + 4]);
            C[2][c + 4] = fmaf(a2, b1[c], C[2][c + 4]);
            C[0][c + 8] = fmaf(a0, b2[c], C[0][c + 8]);
            C[1][c + 8] = fmaf(a1, b2[c], C[1][c + 8]);
            C[2][c + 8] = fmaf(a2, b2[c], C[2][c + 8]);
        }
    }
    #pragma unroll
    for (int r = 0; r < 3; ++r)             // stage t1^T (stride-48 scatter)
        #pragma unroll
        for (int c = 0; c < 12; ++c) scr[(q0 + c) * 48 + p0 + r] = C[r][c];
    // boundary matvecs: wt=VinvB*Pt, wb=VinvB*Pb, vl=VinvA*Pl, vr=VinvA*Pr
    if (lane < 48) {
        float wt = 0.f, wb = 0.f, vl = 0.f, vr = 0.f;
        #pragma unroll 2
        for (int j0 = 0; j0 < 48; j0 += 4) {
            const v4 pt = *(const v4*)&src[48 + j0];
            const v4 pb = *(const v4*)&src[46 * 48 + j0];
            #pragma unroll
            for (int jj = 0; jj < 4; ++jj) {
                int j = j0 + jj;
                float plj = src[j * 48 + 1], prj = src[j * 48 + 46];
                float qr = QR[j * 48 + lane], ql = QLT[j * 48 + lane];
                wt = fmaf(qr, pt[jj], wt); wb = fmaf(qr, pb[jj], wb);
                vl = fmaf(ql, plj, vl);    vr = fmaf(ql, prj, vr);
            }
        }
        vecs[0][lane] = wt; vecs[1][lane] = wb;
        vecs[2][lane] = vl; vecs[3][lane] = vr;
    }
    // ---- M2: uh0 = t1 * V_B^-T ----
    #pragma unroll
    for (int r = 0; r < 3; ++r)
        #pragma unroll
        for (int c = 0; c < 12; ++c) D[r][c] = 0.f;
    #pragma unroll 4
    for (int j = 0; j < 48; ++j) {
        float a0 = scr[j * 48 + p0], a1 = scr[j * 48 + p0 + 1], a2 = scr[j * 48 + p0 + 2];
        const v4 b0 = *(const v4*)&QR[j * 48 + q0];
        const v4 b1 = *(const v4*)&QR[j * 48 + q0 + 4];
        const v4 b2 = *(const v4*)&QR[j * 48 + q0 + 8];
        #pragma unroll
        for (int c = 0; c < 4; ++c) {
            D[0][c]     = fmaf(a0, b0[c], D[0][c]);
            D[1][c]     = fmaf(a1, b0[c], D[1][c]);
            D[2][c]     = fmaf(a2, b0[c], D[2][c]);
            D[0][c + 4] = fmaf(a0, b1[c], D[0][c + 4]);
            D[1][c + 4] = fmaf(a1, b1[c], D[1][c + 4]);
            D[2][c + 4] = fmaf(a2, b1[c], D[2][c + 4]);
            D[0][c + 8] = fmaf(a0, b2[c], D[0][c + 8]);
            D[1][c + 8] = fmaf(a1, b2[c], D[1][c + 8]);
            D[2][c + 8] = fmaf(a2, b2[c], D[2][c + 8]);
        }
    }
    // ---- combine: uhN = G .* uh0 + S .* ch (vectorized tables + writes) ----
    {
        const v4 wt0 = *(const v4*)&vecs[0][q0];
        const v4 wt1 = *(const v4*)&vecs[0][q0 + 4];
        const v4 wt2 = *(const v4*)&vecs[0][q0 + 8];
        const v4 wb0 = *(const v4*)&vecs[1][q0];
        const v4 wb1 = *(const v4*)&vecs[1][q0 + 4];
        const v4 wb2 = *(const v4*)&vecs[1][q0 + 8];
        const v4 rr0 = *(const v4*)&ws[WS_QC0 + 96 + q0];
        const v4 rr1 = *(const v4*)&ws[WS_QC0 + 96 + q0 + 4];
        const v4 rr2 = *(const v4*)&ws[WS_QC0 + 96 + q0 + 8];
        const v4 rs0 = *(const v4*)&ws[WS_QC47 + 96 + q0];
        const v4 rs1 = *(const v4*)&ws[WS_QC47 + 96 + q0 + 4];
        const v4 rs2 = *(const v4*)&ws[WS_QC47 + 96 + q0 + 8];
        #pragma unroll
        for (int r = 0; r < 3; ++r) {
            int p = p0 + r;
            float qc0v = ws[WS_QC0 + p], qc47v = ws[WS_QC47 + p];
            float vlp = vecs[2][p], vrp = vecs[3][p];
            const v4 g0 = *(const v4*)&Gt[p * 48 + q0];
            const v4 g1 = *(const v4*)&Gt[p * 48 + q0 + 4];
            const v4 g2 = *(const v4*)&Gt[p * 48 + q0 + 8];
            const v4 s0 = *(const v4*)&St[p * 48 + q0];
            const v4 s1 = *(const v4*)&St[p * 48 + q0 + 4];
            const v4 s2 = *(const v4*)&St[p * 48 + q0 + 8];
            v4 o0, o1, o2;
            #pragma unroll
            for (int c = 0; c < 4; ++c) {
                float ch0 = qc0v * wt0[c] + qc47v * wb0[c] + vlp * rr0[c] + vrp * rs0[c];
                float ch1 = qc0v * wt1[c] + qc47v * wb1[c] + vlp * rr1[c] + vrp * rs1[c];
                float ch2 = qc0v * wt2[c] + qc47v * wb2[c] + vlp * rr2[c] + vrp * rs2[c];
                o0[c] = g0[c] * D[r][c]     + s0[c] * ch0;
                o1[c] = g1[c] * D[r][c + 4] + s1[c] * ch1;
                o2[c] = g2[c] * D[r][c + 8] + s2[c] * ch2;
            }
            *(v4*)&scr[p * 48 + q0]     = o0;
            *(v4*)&scr[p * 48 + q0 + 4] = o1;
            *(v4*)&scr[p * 48 + q0 + 8] = o2;
        }
    }
    // ---- M3: t2 = V_A * uhN ----
    #pragma unroll
    for (int r = 0; r < 3; ++r)
        #pragma unroll
        for (int c = 0; c < 12; ++c) C[r][c] = 0.f;
    #pragma unroll 4
    for (int k = 0; k < 48; ++k) {
        float a0 = PLT[k * 48 + p0], a1 = PLT[k * 48 + p0 + 1], a2 = PLT[k * 48 + p0 + 2];
        const v4 b0 = *(const v4*)&scr[k * 48 + q0];
        const v4 b1 = *(const v4*)&scr[k * 48 + q0 + 4];
        const v4 b2 = *(const v4*)&scr[k * 48 + q0 + 8];
        #pragma unroll
        for (int c = 0; c < 4; ++c) {
            C[0][c]     = fmaf(a0, b0[c], C[0][c]);
            C[1][c]     = fmaf(a1, b0[c], C[1][c]);
            C[2][c]     = fmaf(a2, b0[c], C[2][c]);
            C[0][c + 4] = fmaf(a0, b1[c], C[0][c + 4]);
            C[1][c + 4] = fmaf(a1, b1[c], C[1][c + 4]);
            C[2][c + 4] = fmaf(a2, b1[c], C[2][c + 4]);
            C[0][c + 8] = fmaf(a0, b2[c], C[0][c + 8]);
            C[1][c + 8] = fmaf(a1, b2[c], C[1][c + 8]);
            C[2][c + 8] = fmaf(a2, b2[c], C[2][c + 8]);
        }
    }
    #pragma unroll
    for (int r = 0; r < 3; ++r)             // stage t2^T (stride-48 scatter)
        #pragma unroll
        for (int c = 0; c < 12; ++c) scr[(q0 + c) * 48 + p0 + r] = C[r][c];
    // ---- M4: uN = t2 * V_B^T ----
    #pragma unroll
    for (int r = 0; r < 3; ++r)
        #pragma unroll
        for (int c = 0; c < 12; ++c) D[r][c] = 0.f;
    #pragma unroll 4
    for (int q = 0; q < 48; ++q) {
        float a0 = scr[q * 48 + p0], a1 = scr[q * 48 + p0 + 1], a2 = scr[q * 48 + p0 + 2];
        const v4 b0 = *(const v4*)&PR[q * 48 + q0];
        const v4 b1 = *(const v4*)&PR[q * 48 + q0 + 4];
        const v4 b2 = *(const v4*)&PR[q * 48 + q0 + 8];
        #pragma unroll
        for (int c = 0; c < 4; ++c) {
            D[0][c]     = fmaf(a0, b0[c], D[0][c]);
            D[1][c]     = fmaf(a1, b0[c], D[1][c]);
            D[2][c]     = fmaf(a2, b0[c], D[2][c]);
            D[0][c + 4] = fmaf(a0, b1[c], D[0][c + 4]);
            D[1][c + 4] = fmaf(a1, b1[c], D[1][c + 4]);
            D[2][c + 4] = fmaf(a2, b1[c], D[2][c + 4]);
            D[0][c + 8] = fmaf(a0, b2[c], D[0][c + 8]);
            D[1][c + 8] = fmaf(a1, b2[c], D[1][c + 8]);
            D[2][c + 8] = fmaf(a2, b2[c], D[2][c + 8]);
        }
    }
    #pragma unroll
    for (int r = 0; r < 3; ++r) {
        v4 o0, o1, o2;
        #pragma unroll
        for (int c = 0; c < 4; ++c) { o0[c] = D[r][c]; o1[c] = D[r][c + 4]; o2[c] = D[r][c + 8]; }
        *(v4*)&dst[(p0 + r) * 48 + q0]     = o0;
        *(v4*)&dst[(p0 + r) * 48 + q0 + 4] = o1;
        *(v4*)&dst[(p0 + r) * 48 + q0 + 8] = o2;
    }
}

extern "C" void kernel_launch(void* const* d_in, const int* in_sizes, int n_in,
                              void* d_out, int out_size, void* d_ws, size_t ws_size,
                              hipStream_t stream) {
    const float* u0 = (const float*)d_in[0];
    float* ws = (float*)d_ws;
    eig_kernel<<<2, 64, 0, stream>>>(
        (const float*)d_in[1], (const float*)d_in[2], (const float*)d_in[3],
        (const float*)d_in[4], (const float*)d_in[5], (const float*)d_in[6], ws);
    gs_kernel<<<9, 256, 0, stream>>>(ws);
    prop_kernel<<<8192, 64, 0, stream>>>(u0, ws, (float*)d_out);
}